// Round 4
// baseline (22.335 us; speedup 1.0000x reference)
//
#include <hip/hip_runtime.h>

typedef float  f32x4  __attribute__((ext_vector_type(4)));
typedef short  bf16x8 __attribute__((ext_vector_type(8)));

#define Bb 256

// packed f32->bf16 (RNE), gfx950
__device__ __forceinline__ uint cvtpk(float lo, float hi) {
    uint r;
    asm("v_cvt_pk_bf16_f32 %0, %1, %2" : "=v"(r) : "v"(lo), "v"(hi));
    return r;
}
__device__ __forceinline__ ushort f2b1(float v) { return (ushort)cvtpk(v, v); }
__device__ __forceinline__ float bflo(uint u) { return __uint_as_float(u << 16); }
__device__ __forceinline__ float bfhi(uint u) { return __uint_as_float(u & 0xffff0000u); }

union U8 { uint u[4]; bf16x8 v; };

__global__ __launch_bounds__(512, 4) void gcm_kernel(
    const float* __restrict__ obs,      // B*N*D
    const float* __restrict__ enc_w,    // D*H
    const float* __restrict__ enc_b,    // H
    const float* __restrict__ gate_w1,  // 2H*H
    const float* __restrict__ gate_b1,  // H
    const float* __restrict__ gate_w2,  // H
    const float* __restrict__ gate_b2,  // 1
    const float* __restrict__ msg_w1,   // H*H
    const float* __restrict__ msg_b1,   // H
    const float* __restrict__ msg_w2,   // H*H
    const float* __restrict__ msg_b2,   // H
    float* __restrict__ out)            // B*N*H
{
    const int bid  = blockIdx.x;
    const int bb   = bid >> 1;          // batch
    const int half = bid & 1;           // which 32 output rows
    const int t    = threadIdx.x;
    const int lane = t & 63;
    const int wv   = t >> 6;            // 0..7
    const int lr   = lane & 15;
    const int lg   = lane >> 4;
    const int rt   = wv >> 1;           // row-tile 0..3 (phases 1-3)

    // Aliased LDS arena (74,240 B -> 2 blocks/CU if <=80K effective)
    __shared__ __align__(16) char arena[74240];
    ushort* s_wT     = (ushort*)(arena);           // 32K [n<256][k<64] swz e^=(n&7)<<3 ; wi|wj|mw1|mw2 (T)
    ushort* s_encwT  = (ushort*)(arena + 32768);   // 16K [n<64][k<128] swz (dead after P1)
    float*  s_gi     = (float*) (arena + 32768);   //  8K [r<32][h<64] swz e^=(r&7)<<2 (alias encwT, written P2)
    ushort* s_gatesb = (ushort*)(arena + 40960);   //  4K [r<32][j<64] swz (alias encwT hi, written gates)
    ushort* s_enc    = (ushort*)(arena + 49152);   //  8K [r<64][h<64] swz (dead after P2)
    ushort* s_msgT   = (ushort*)(arena + 49152);   //  8K [h<64][j<64] swz (alias enc, written P3)
    ushort* s_msgh   = (ushort*)(arena + 57344);   //  8K [r<64][h<64] swz
    ushort* s_gjb    = (ushort*)(arena + 65536);   //  8.5K [j<64][h<64] stride 68, bf16, no swz

    // ---- staging: issue obs loads (deep latency first) ----
    float4 pf[8];
    {
        const float* ob = obs + ((size_t)bb * 64 + rt * 16 + lr) * 128 + lg * 8;
        #pragma unroll
        for (int ks = 0; ks < 4; ++ks) {
            pf[2 * ks]     = *(const float4*)(ob + ks * 32);
            pf[2 * ks + 1] = *(const float4*)(ob + ks * 32 + 4);
        }
    }
    // ---- enc_w loads ----
    float4 pe[4];
    #pragma unroll
    for (int it = 0; it < 4; ++it) {
        const int idx = t + it * 512;          // 0..2047
        const int k   = idx >> 4;              // 0..127
        const int n0  = (idx & 15) * 4;
        pe[it] = *(const float4*)(enc_w + k * 64 + n0);
    }
    // ---- obs -> bf16 A-fragments (frees pf) ----
    bf16x8 afrag[4];
    #pragma unroll
    for (int ks = 0; ks < 4; ++ks) {
        U8 u;
        u.u[0] = cvtpk(pf[2 * ks].x,     pf[2 * ks].y);
        u.u[1] = cvtpk(pf[2 * ks].z,     pf[2 * ks].w);
        u.u[2] = cvtpk(pf[2 * ks + 1].x, pf[2 * ks + 1].y);
        u.u[3] = cvtpk(pf[2 * ks + 1].z, pf[2 * ks + 1].w);
        afrag[ks] = u.v;
    }
    // ---- enc_w -> s_encwT bf16 swizzled (frees pe) ----
    #pragma unroll
    for (int it = 0; it < 4; ++it) {
        const int idx = t + it * 512;
        const int k   = idx >> 4;
        const int n0  = (idx & 15) * 4;
        uint pA = cvtpk(pe[it].x, pe[it].y), pB = cvtpk(pe[it].z, pe[it].w);
        s_encwT[((n0 + 0) * 128 + k) ^ (((n0 + 0) & 7) << 3)] = (ushort)pA;
        s_encwT[((n0 + 1) * 128 + k) ^ (((n0 + 1) & 7) << 3)] = (ushort)(pA >> 16);
        s_encwT[((n0 + 2) * 128 + k) ^ (((n0 + 2) & 7) << 3)] = (ushort)pB;
        s_encwT[((n0 + 3) * 128 + k) ^ (((n0 + 3) & 7) << 3)] = (ushort)(pB >> 16);
    }
    // ---- issue wT loads (land during P1) ----
    float4 pfw[8];
    {
        const int k  = t >> 4;                 // 0..31
        const int n0 = (t & 15) * 4;
        #pragma unroll
        for (int kh = 0; kh < 2; ++kh) {
            const int kk = k + kh * 32;
            pfw[0 * 2 + kh] = *(const float4*)(gate_w1 + kk * 64 + n0);        // w_i
            pfw[1 * 2 + kh] = *(const float4*)(gate_w1 + (64 + kk) * 64 + n0); // w_j
            pfw[2 * 2 + kh] = *(const float4*)(msg_w1 + kk * 64 + n0);
            pfw[3 * 2 + kh] = *(const float4*)(msg_w2 + kk * 64 + n0);
        }
    }
    __syncthreads();   // B1: s_encwT ready

    // ---------- P1: enc = relu(obs @ enc_w + b); wave: rt x 2 col-tiles ----------
    {
        f32x4 acc[2];
        acc[0] = (f32x4){0.f, 0.f, 0.f, 0.f};
        acc[1] = (f32x4){0.f, 0.f, 0.f, 0.f};
        #pragma unroll
        for (int ks = 0; ks < 4; ++ks) {
            const int k0 = ks * 32 + lg * 8;
            #pragma unroll
            for (int jj = 0; jj < 2; ++jj) {
                const int n = (wv & 1) * 32 + jj * 16 + lr;
                bf16x8 bf = *(const bf16x8*)(s_encwT + ((n * 128 + k0) ^ ((n & 7) << 3)));
                acc[jj] = __builtin_amdgcn_mfma_f32_16x16x32_bf16(afrag[ks], bf, acc[jj], 0, 0, 0);
            }
        }
        // stage wT while MFMAs drain
        {
            const int k  = t >> 4;
            const int n00 = (t & 15) * 4;
            #pragma unroll
            for (int m = 0; m < 4; ++m) {
                #pragma unroll
                for (int kh = 0; kh < 2; ++kh) {
                    float4 w4 = pfw[m * 2 + kh];
                    const int kk = k + kh * 32;
                    const int nb = m * 64 + n00;
                    uint pA = cvtpk(w4.x, w4.y), pB = cvtpk(w4.z, w4.w);
                    s_wT[((nb + 0) * 64 + kk) ^ (((nb + 0) & 7) << 3)] = (ushort)pA;
                    s_wT[((nb + 1) * 64 + kk) ^ (((nb + 1) & 7) << 3)] = (ushort)(pA >> 16);
                    s_wT[((nb + 2) * 64 + kk) ^ (((nb + 2) & 7) << 3)] = (ushort)pB;
                    s_wT[((nb + 3) * 64 + kk) ^ (((nb + 3) & 7) << 3)] = (ushort)(pB >> 16);
                }
            }
        }
        // epilogue: bias+relu -> s_enc bf16
        const int rb = rt * 16 + lg * 4;
        #pragma unroll
        for (int jj = 0; jj < 2; ++jj) {
            const int n = (wv & 1) * 32 + jj * 16 + lr;
            const float be = enc_b[n];
            #pragma unroll
            for (int rr = 0; rr < 4; ++rr) {
                const int row = rb + rr;
                float v = fmaxf(acc[jj][rr] + be, 0.f);
                s_enc[(row * 64 + n) ^ ((row & 7) << 3)] = f2b1(v);
            }
        }
    }
    __syncthreads();   // B2: s_enc + s_wT ready

    // ---------- P2: [gi|gj|msgh] = enc @ [wi|wj|mw1]; 6 col-tiles/wave ----------
    {
        f32x4 acc[6];
        #pragma unroll
        for (int q = 0; q < 6; ++q) acc[q] = (f32x4){0.f, 0.f, 0.f, 0.f};
        const int arow = rt * 16 + lr;
        #pragma unroll
        for (int ks = 0; ks < 2; ++ks) {
            const int k0 = ks * 32 + lg * 8;
            bf16x8 a = *(const bf16x8*)(s_enc + ((arow * 64 + k0) ^ ((arow & 7) << 3)));
            #pragma unroll
            for (int q = 0; q < 6; ++q) {
                const int n = ((wv & 1) * 6 + q) * 16 + lr;
                bf16x8 bf = *(const bf16x8*)(s_wT + ((n * 64 + k0) ^ ((n & 7) << 3)));
                acc[q] = __builtin_amdgcn_mfma_f32_16x16x32_bf16(a, bf, acc[q], 0, 0, 0);
            }
        }
        const int rb = rt * 16 + lg * 4;
        #pragma unroll
        for (int q = 0; q < 6; ++q) {
            const int nfull = ((wv & 1) * 6 + q) * 16;
            const int cc = nfull + lr;
            if (nfull < 64) {                       // gi: only own half's rows, f32 swizzled
                if ((rt >> 1) == half) {
                    const int lb = rb - half * 32;  // local row base 0..28
                    #pragma unroll
                    for (int rr = 0; rr < 4; ++rr) {
                        const int row = lb + rr;
                        s_gi[(row * 64 + cc) ^ ((row & 7) << 2)] = acc[q][rr];
                    }
                }
            } else if (nfull < 128) {               // gj + b1 -> bf16 [j][68]
                const float b1 = gate_b1[cc - 64];
                #pragma unroll
                for (int rr = 0; rr < 4; ++rr)
                    s_gjb[(rb + rr) * 68 + (cc - 64)] = f2b1(acc[q][rr] + b1);
            } else {                                // msgh = relu(.+msg_b1) bf16 swz
                const float bm = msg_b1[cc - 128];
                float v0 = fmaxf(acc[q][0] + bm, 0.f), v1 = fmaxf(acc[q][1] + bm, 0.f);
                float v2 = fmaxf(acc[q][2] + bm, 0.f), v3 = fmaxf(acc[q][3] + bm, 0.f);
                uint pA = cvtpk(v0, v1), pB = cvtpk(v2, v3);
                const int c2 = cc - 128;
                s_msgh[((rb + 0) * 64 + c2) ^ (((rb + 0) & 7) << 3)] = (ushort)pA;
                s_msgh[((rb + 1) * 64 + c2) ^ (((rb + 1) & 7) << 3)] = (ushort)(pA >> 16);
                s_msgh[((rb + 2) * 64 + c2) ^ (((rb + 2) & 7) << 3)] = (ushort)pB;
                s_msgh[((rb + 3) * 64 + c2) ^ (((rb + 3) & 7) << 3)] = (ushort)(pB >> 16);
            }
        }
    }
    __syncthreads();   // B3: gi/gjb/msgh ready; enc dead

    // ---------- P3: msg = msgh @ mw2 + b2 -> s_msgT bf16 [h][j] (aliases enc) ----------
    {
        f32x4 acc[2];
        acc[0] = (f32x4){0.f, 0.f, 0.f, 0.f};
        acc[1] = (f32x4){0.f, 0.f, 0.f, 0.f};
        const int arow = rt * 16 + lr;
        #pragma unroll
        for (int ks = 0; ks < 2; ++ks) {
            const int k0 = ks * 32 + lg * 8;
            bf16x8 a = *(const bf16x8*)(s_msgh + ((arow * 64 + k0) ^ ((arow & 7) << 3)));
            #pragma unroll
            for (int jj = 0; jj < 2; ++jj) {
                const int n = 192 + ((wv & 1) * 2 + jj) * 16 + lr;
                bf16x8 bf = *(const bf16x8*)(s_wT + ((n * 64 + k0) ^ ((n & 7) << 3)));
                acc[jj] = __builtin_amdgcn_mfma_f32_16x16x32_bf16(a, bf, acc[jj], 0, 0, 0);
            }
        }
        const int jb = rt * 16 + lg * 4;
        #pragma unroll
        for (int jj = 0; jj < 2; ++jj) {
            const int h = ((wv & 1) * 2 + jj) * 16 + lr;
            const float bm2 = msg_b2[h];
            uint pA = cvtpk(acc[jj][0] + bm2, acc[jj][1] + bm2);
            uint pB = cvtpk(acc[jj][2] + bm2, acc[jj][3] + bm2);
            const int e = (h * 64 + jb) ^ ((h & 7) << 3);
            *(uint*)(s_msgT + e)     = pA;
            *(uint*)(s_msgT + e + 2) = pB;
        }
    }

    // ---------- gates: rows = half*32 + wv*4 + r, j = lane ----------
    {
        const int lrow0 = wv * 4;
        float ag[4] = {0.f, 0.f, 0.f, 0.f};
        const ushort* gjrow = s_gjb + lane * 68;
        #pragma unroll
        for (int h0 = 0; h0 < 64; h0 += 8) {
            uint2 pj0 = *(const uint2*)(gjrow + h0);       // h0..h0+3 (bf16 pairs)
            uint2 pj1 = *(const uint2*)(gjrow + h0 + 4);   // h0+4..h0+7
            float gj0 = bflo(pj0.x), gj1 = bfhi(pj0.x), gj2 = bflo(pj0.y), gj3 = bfhi(pj0.y);
            float gj4 = bflo(pj1.x), gj5 = bfhi(pj1.x), gj6 = bflo(pj1.y), gj7 = bfhi(pj1.y);
            float4 w2a = *(const float4*)(gate_w2 + h0);       // uniform -> s_load
            float4 w2b = *(const float4*)(gate_w2 + h0 + 4);
            #pragma unroll
            for (int r = 0; r < 4; ++r) {
                const int row = lrow0 + r;
                float4 gia = *(const float4*)(s_gi + ((row * 64 + h0) ^ ((row & 7) << 2)));
                float4 gib = *(const float4*)(s_gi + ((row * 64 + h0 + 4) ^ ((row & 7) << 2)));
                ag[r] = fmaf(fmaxf(gia.x + gj0, 0.f), w2a.x, ag[r]);
                ag[r] = fmaf(fmaxf(gia.y + gj1, 0.f), w2a.y, ag[r]);
                ag[r] = fmaf(fmaxf(gia.z + gj2, 0.f), w2a.z, ag[r]);
                ag[r] = fmaf(fmaxf(gia.w + gj3, 0.f), w2a.w, ag[r]);
                ag[r] = fmaf(fmaxf(gib.x + gj4, 0.f), w2b.x, ag[r]);
                ag[r] = fmaf(fmaxf(gib.y + gj5, 0.f), w2b.y, ag[r]);
                ag[r] = fmaf(fmaxf(gib.z + gj6, 0.f), w2b.z, ag[r]);
                ag[r] = fmaf(fmaxf(gib.w + gj7, 0.f), w2b.w, ag[r]);
            }
        }
        const float b2v = gate_b2[0];
        #pragma unroll
        for (int r = 0; r < 4; ++r) {
            const int row = lrow0 + r;
            const float g = 1.f / (1.f + __expf(-(ag[r] + b2v)));
            s_gatesb[(row * 64 + lane) ^ ((row & 7) << 3)] = f2b1(g);
        }
    }
    __syncthreads();   // B4: gatesb + msgT ready

    // ---------- P5: enhanced = gates @ msg (MFMA); own 32 rows ----------
    {
        const int rtl = wv >> 2;            // 0..1 local row-tile
        const int ct  = wv & 3;
        f32x4 acc = (f32x4){0.f, 0.f, 0.f, 0.f};
        const int arow = rtl * 16 + lr;
        const int n = ct * 16 + lr;
        #pragma unroll
        for (int ks = 0; ks < 2; ++ks) {
            const int k0 = ks * 32 + lg * 8;
            bf16x8 a  = *(const bf16x8*)(s_gatesb + ((arow * 64 + k0) ^ ((arow & 7) << 3)));
            bf16x8 bf = *(const bf16x8*)(s_msgT   + ((n * 64 + k0) ^ ((n & 7) << 3)));
            acc = __builtin_amdgcn_mfma_f32_16x16x32_bf16(a, bf, acc, 0, 0, 0);
        }
        const int rb = half * 32 + rtl * 16 + lg * 4;
        #pragma unroll
        for (int rr = 0; rr < 4; ++rr)
            out[((size_t)bb * 64 + rb + rr) * 64 + n] = acc[rr];
    }
}

extern "C" void kernel_launch(void* const* d_in, const int* in_sizes, int n_in,
                              void* d_out, int out_size, void* d_ws, size_t ws_size,
                              hipStream_t stream) {
    const float* obs     = (const float*)d_in[0];
    const float* enc_w   = (const float*)d_in[1];
    const float* enc_b   = (const float*)d_in[2];
    const float* gate_w1 = (const float*)d_in[3];
    const float* gate_b1 = (const float*)d_in[4];
    const float* gate_w2 = (const float*)d_in[5];
    const float* gate_b2 = (const float*)d_in[6];
    const float* msg_w1  = (const float*)d_in[7];
    const float* msg_b1  = (const float*)d_in[8];
    const float* msg_w2  = (const float*)d_in[9];
    const float* msg_b2  = (const float*)d_in[10];
    float* out = (float*)d_out;

    gcm_kernel<<<2 * Bb, 512, 0, stream>>>(obs, enc_w, enc_b, gate_w1, gate_b1,
                                           gate_w2, gate_b2, msg_w1, msg_b1,
                                           msg_w2, msg_b2, out);
}